// Round 3
// baseline (15300.507 us; speedup 1.0000x reference)
//
#include <hip/hip_runtime.h>
#include <cstddef>

// Problem constants (match reference)
constexpr int CB  = 4;      // batch
constexpr int CL  = 2048;   // seq len
constexpr int CDM = 1024;   // model dim
constexpr int CDI = 2048;   // inner dim
constexpr int CNS = 16;     // state dim
constexpr int CR  = 64;     // dt rank

// ---------------------------------------------------------------------------
// Generic fp32 GEMM (NT): C[m,n] = act(sum_k A[m,k]*W[n,k] + bias[n]) (+= opt)
// A: (M, lda) row-major, W: (N, ldw) row-major (both k-contiguous).
// Grid: (N/BN, M/BM), block 256 = 16x16 threads, micro-tile TM x TN interleaved.
// ACT: 0 = none, 1 = softplus. Shapes chosen so no bounds checks needed.
// ---------------------------------------------------------------------------
template<int BM, int BN, int BK, int TM, int TN, int ACT, bool BIAS, bool ACC>
__global__ __launch_bounds__(256)
void gemm_nt(const float* __restrict__ A, int lda,
             const float* __restrict__ W, int ldw,
             const float* __restrict__ bias,
             float* __restrict__ C, int ldc, int Ksz)
{
    __shared__ float As[BM][BK + 4];
    __shared__ float Ws[BN][BK + 4];
    const int tid = threadIdx.x;
    const int tx  = tid & 15;          // n-dim thread coord
    const int ty  = tid >> 4;          // m-dim thread coord
    const int m0  = blockIdx.y * BM;
    const int n0  = blockIdx.x * BN;

    float acc[TM][TN] = {};

    const int rA = tid >> 2;           // 4 threads per row, float4 along k
    const int kq = (tid & 3) * 4;

    for (int k0 = 0; k0 < Ksz; k0 += BK) {
        for (int r = rA; r < BM; r += 64) {
            float4 v = *(const float4*)(A + (size_t)(m0 + r) * lda + (k0 + kq));
            *(float4*)&As[r][kq] = v;
        }
        for (int r = rA; r < BN; r += 64) {
            float4 v = *(const float4*)(W + (size_t)(n0 + r) * ldw + (k0 + kq));
            *(float4*)&Ws[r][kq] = v;
        }
        __syncthreads();
#pragma unroll
        for (int k4 = 0; k4 < BK / 4; ++k4) {
            float4 a4[TM], w4[TN];
#pragma unroll
            for (int i = 0; i < TM; ++i) a4[i] = *(const float4*)&As[ty + 16 * i][k4 * 4];
#pragma unroll
            for (int j = 0; j < TN; ++j) w4[j] = *(const float4*)&Ws[tx + 16 * j][k4 * 4];
#pragma unroll
            for (int i = 0; i < TM; ++i)
#pragma unroll
                for (int j = 0; j < TN; ++j) {
                    acc[i][j] += a4[i].x * w4[j].x;
                    acc[i][j] += a4[i].y * w4[j].y;
                    acc[i][j] += a4[i].z * w4[j].z;
                    acc[i][j] += a4[i].w * w4[j].w;
                }
        }
        __syncthreads();
    }

#pragma unroll
    for (int i = 0; i < TM; ++i) {
        const int m = m0 + ty + 16 * i;
#pragma unroll
        for (int j = 0; j < TN; ++j) {
            const int n = n0 + tx + 16 * j;
            float v = acc[i][j];
            if (BIAS) v += bias[n];
            if (ACT == 1) v = (v > 20.f) ? v : log1pf(__expf(v));  // softplus
            const size_t off = (size_t)m * ldc + n;
            if (ACC) C[off] += v; else C[off] = v;
        }
    }
}

// ---------------------------------------------------------------------------
// LayerNorm over last dim (1024). One block (256 thr) per row, float4 per thr.
// Safe to run in-place (all reads precede writes, separated by barriers).
// ---------------------------------------------------------------------------
__global__ __launch_bounds__(256)
void layernorm_k(const float* __restrict__ in, const float* __restrict__ w,
                 const float* __restrict__ b, float* __restrict__ out)
{
    __shared__ float red[4];
    const int row = blockIdx.x, tid = threadIdx.x;
    const float4 x = *(const float4*)(in + (size_t)row * CDM + tid * 4);

    float s = x.x + x.y + x.z + x.w;
#pragma unroll
    for (int off = 32; off >= 1; off >>= 1) s += __shfl_xor(s, off, 64);
    if ((tid & 63) == 0) red[tid >> 6] = s;
    __syncthreads();
    const float mu = (red[0] + red[1] + red[2] + red[3]) * (1.f / CDM);
    __syncthreads();

    float4 d;
    d.x = x.x - mu; d.y = x.y - mu; d.z = x.z - mu; d.w = x.w - mu;
    float ss = d.x * d.x + d.y * d.y + d.z * d.z + d.w * d.w;
#pragma unroll
    for (int off = 32; off >= 1; off >>= 1) ss += __shfl_xor(ss, off, 64);
    if ((tid & 63) == 0) red[tid >> 6] = ss;
    __syncthreads();
    const float var = (red[0] + red[1] + red[2] + red[3]) * (1.f / CDM);
    const float rs = rsqrtf(var + 1e-5f);

    const float4 wv = *(const float4*)(w + tid * 4);
    const float4 bv = *(const float4*)(b + tid * 4);
    float4 o;
    o.x = d.x * rs * wv.x + bv.x;
    o.y = d.y * rs * wv.y + bv.y;
    o.z = d.z * rs * wv.z + bv.z;
    o.w = d.w * rs * wv.w + bv.w;
    *(float4*)(out + (size_t)row * CDM + tid * 4) = o;
}

// ---------------------------------------------------------------------------
// Causal depthwise conv (K=4) + SiLU. rev=1 uses the anti-causal window
// (== reversed-sequence conv written back at original positions).
// u layout: (nb*L, DI). One thread per (b,t,c); b decoded from idx (0 if the
// grid covers a single batch element).
// ---------------------------------------------------------------------------
__global__ __launch_bounds__(256)
void conv_silu_k(const float* __restrict__ u, const float* __restrict__ cw,
                 const float* __restrict__ cb, float* __restrict__ uc, int rev)
{
    const int idx = blockIdx.x * 256 + threadIdx.x;
    const int c = idx & (CDI - 1);
    const int t = (idx >> 11) & (CL - 1);
    const int b = idx >> 22;
    const size_t rb = (size_t)b * CL;

    float s = cb[c];
#pragma unroll
    for (int k = 0; k < 4; ++k) {
        const int tsrc = rev ? (t + 3 - k) : (t - 3 + k);
        if (tsrc >= 0 && tsrc < CL)
            s += cw[c * 4 + k] * u[(rb + tsrc) * CDI + c];
    }
    s = s / (1.f + __expf(-s));   // silu
    uc[(rb + t) * CDI + c] = s;
}

// ---------------------------------------------------------------------------
// Selective scan. lane = state index n (16), 16 channels per 256-thr block.
// Grid: nb * DI/16 blocks. Fuses D-skip and z-gating; y overwrites uc in
// place (safe: the 16-lane group reads u before lane 0 writes y there).
// ---------------------------------------------------------------------------
__global__ __launch_bounds__(256)
void scan_k(const float* __restrict__ dt, const float* __restrict__ ucin,
            const float* __restrict__ xdbl, const float* __restrict__ z,
            const float* __restrict__ A_log, const float* __restrict__ Dsk,
            float* __restrict__ yout, int rev)
{
    const int tid = threadIdx.x;
    const int n = tid & 15;
    const int c = ((blockIdx.x & 127) << 4) + (tid >> 4);
    const int b = blockIdx.x >> 7;

    const float Acn = -__expf(A_log[c * CNS + n]);
    const float Dc  = Dsk[c];
    const size_t rb = (size_t)b * CL;

    float h = 0.f;
    for (int tt = 0; tt < CL; ++tt) {
        const int t = rev ? (CL - 1 - tt) : tt;
        const size_t rid = rb + t;
        const float dtv = dt[rid * CDI + c];
        const float uv  = ucin[rid * CDI + c];
        const float Bn  = xdbl[rid * 96 + 64 + n];
        const float Cn  = xdbl[rid * 96 + 80 + n];

        h = __expf(dtv * Acn) * h + (dtv * uv) * Bn;
        float p = h * Cn;
        p += __shfl_xor(p, 8, 16);
        p += __shfl_xor(p, 4, 16);
        p += __shfl_xor(p, 2, 16);
        p += __shfl_xor(p, 1, 16);
        if (n == 0) {
            const float zv = z[rid * CDI + c];
            float yv = p + Dc * uv;
            yv *= zv / (1.f + __expf(-zv));   // * silu(z)
            yout[rid * CDI + c] = yv;
        }
    }
}

// ---------------------------------------------------------------------------
extern "C" void kernel_launch(void* const* d_in, const int* in_sizes, int n_in,
                              void* d_out, int out_size, void* d_ws, size_t ws_size,
                              hipStream_t stream)
{
    (void)in_sizes; (void)n_in; (void)out_size;
    const float* x      = (const float*)d_in[0];
    const float* norm_w = (const float*)d_in[1];
    const float* norm_b = (const float*)d_in[2];
    const float* in_w   = (const float*)d_in[3];
    const float* conv_w = (const float*)d_in[4];
    const float* conv_b = (const float*)d_in[5];
    const float* xp_w   = (const float*)d_in[6];
    const float* dt_w   = (const float*)d_in[7];
    const float* dt_b   = (const float*)d_in[8];
    const float* A_log  = (const float*)d_in[9];
    const float* Dsk    = (const float*)d_in[10];
    const float* out_w  = (const float*)d_in[11];
    const float* proj_w = (const float*)d_in[12];
    const float* proj_b = (const float*)d_in[13];
    const float* fn_w   = (const float*)d_in[14];
    const float* fn_b   = (const float*)d_in[15];

    float* ws   = (float*)d_ws;
    float* hbuf = (float*)d_out;                 // LN output scratch (32 MB, free)

    // Fast path footprint (floats): hs 8M | A(u/dtb) 16M | Z(z/tmp) 16M |
    // uc 16M | xdbl 0.75M  => 59,506,688 floats = 227 MB
    const size_t F_HS = 8u * 1024 * 1024;
    const size_t F_BIG = 16u * 1024 * 1024;
    const size_t need_fast = (F_HS + 3 * F_BIG + 786432) * sizeof(float);

    if (ws_size >= need_fast) {
        // ----------------- fast path: full batch per kernel ----------------
        float* hs   = ws;                        // (B,L,DM) residual
        float* Abuf = hs   + F_HS;               // u, then dtb   (B,L,DI)
        float* Zbuf = Abuf + F_BIG;              // z, then tmp   (B,L,DI)
        float* uc   = Zbuf + F_BIG;              // conv out / y  (B,L,DI)
        float* xdbl = uc   + F_BIG;              // (B,L,96) delta|B|C

        hipMemcpyAsync(hs, x, F_HS * sizeof(float), hipMemcpyDeviceToDevice, stream);
        const int rows = CB * CL;  // 8192

        for (int l = 0; l < 2; ++l) {
            layernorm_k<<<rows, 256, 0, stream>>>(hs, norm_w + l * CDM, norm_b + l * CDM, hbuf);
            for (int d = 0; d < 2; ++d) {
                const int pd = l * 2 + d;
                const float* iw = in_w + (size_t)pd * 4096 * CDM;
                // u = h @ in_w[:2048]^T ; z = h @ in_w[2048:4096]^T
                gemm_nt<128,128,16,8,8,0,false,false><<<dim3(CDI/128, rows/128), 256, 0, stream>>>(
                    hbuf, CDM, iw, CDM, nullptr, Abuf, CDI, CDM);
                gemm_nt<128,128,16,8,8,0,false,false><<<dim3(CDI/128, rows/128), 256, 0, stream>>>(
                    hbuf, CDM, iw + (size_t)CDI * CDM, CDM, nullptr, Zbuf, CDI, CDM);
                conv_silu_k<<<(rows * CDI) / 256, 256, 0, stream>>>(
                    Abuf, conv_w + pd * CDI * 4, conv_b + pd * CDI, uc, d);
                gemm_nt<64,96,16,4,6,0,false,false><<<dim3(1, rows/64), 256, 0, stream>>>(
                    uc, CDI, xp_w + (size_t)pd * 96 * CDI, CDI, nullptr, xdbl, 96, CDI);
                gemm_nt<128,128,16,8,8,1,true,false><<<dim3(CDI/128, rows/128), 256, 0, stream>>>(
                    xdbl, 96, dt_w + (size_t)pd * CDI * CR, CR, dt_b + pd * CDI, Abuf, CDI, CR);
                scan_k<<<CB * (CDI / 16), 256, 0, stream>>>(
                    Abuf, uc, xdbl, Zbuf, A_log + pd * CDI * CNS, Dsk + pd * CDI, uc, d);
                // tmp = y @ out_w^T   (reuses Zbuf; z is dead after the scan)
                gemm_nt<128,128,16,8,8,0,false,false><<<dim3(CDM/128, rows/128), 256, 0, stream>>>(
                    uc, CDI, out_w + (size_t)pd * CDM * CDI, CDI, nullptr, Zbuf, CDM, CDI);
                // hs += tmp @ proj_w[:, d*1024:+1024]^T  (+ proj_b once, on d==0)
                const float* pw = proj_w + (size_t)l * CDM * 2048 + d * CDM;
                if (d == 0)
                    gemm_nt<128,128,16,8,8,0,true,true><<<dim3(CDM/128, rows/128), 256, 0, stream>>>(
                        Zbuf, CDM, pw, 2048, proj_b + l * CDM, hs, CDM, CDM);
                else
                    gemm_nt<128,128,16,8,8,0,false,true><<<dim3(CDM/128, rows/128), 256, 0, stream>>>(
                        Zbuf, CDM, pw, 2048, nullptr, hs, CDM, CDM);
            }
        }
        layernorm_k<<<rows, 256, 0, stream>>>(hs, fn_w, fn_b, (float*)d_out);
    } else {
        // -------------- chunked path: one batch element at a time ----------
        // Footprint: hs 8M | A 4M | Z 4M | uc 4M | xdbl 0.1875M = 81 MB
        const size_t F_B = 4u * 1024 * 1024;
        float* hs   = ws;
        float* Abuf = hs   + F_HS;
        float* Zbuf = Abuf + F_B;
        float* uc   = Zbuf + F_B;
        float* xdbl = uc   + F_B;

        hipMemcpyAsync(hs, x, F_HS * sizeof(float), hipMemcpyDeviceToDevice, stream);
        const int rows = CL;  // 2048 per batch element

        for (int l = 0; l < 2; ++l) {
            layernorm_k<<<CB * CL, 256, 0, stream>>>(hs, norm_w + l * CDM, norm_b + l * CDM, hbuf);
            for (int d = 0; d < 2; ++d) {
                const int pd = l * 2 + d;
                const float* iw = in_w + (size_t)pd * 4096 * CDM;
                const float* pw = proj_w + (size_t)l * CDM * 2048 + d * CDM;
                for (int b = 0; b < CB; ++b) {
                    const float* hb = hbuf + (size_t)b * CL * CDM;
                    float* hsb = hs + (size_t)b * CL * CDM;
                    gemm_nt<128,128,16,8,8,0,false,false><<<dim3(CDI/128, rows/128), 256, 0, stream>>>(
                        hb, CDM, iw, CDM, nullptr, Abuf, CDI, CDM);
                    gemm_nt<128,128,16,8,8,0,false,false><<<dim3(CDI/128, rows/128), 256, 0, stream>>>(
                        hb, CDM, iw + (size_t)CDI * CDM, CDM, nullptr, Zbuf, CDI, CDM);
                    conv_silu_k<<<(rows * CDI) / 256, 256, 0, stream>>>(
                        Abuf, conv_w + pd * CDI * 4, conv_b + pd * CDI, uc, d);
                    gemm_nt<64,96,16,4,6,0,false,false><<<dim3(1, rows/64), 256, 0, stream>>>(
                        uc, CDI, xp_w + (size_t)pd * 96 * CDI, CDI, nullptr, xdbl, 96, CDI);
                    gemm_nt<128,128,16,8,8,1,true,false><<<dim3(CDI/128, rows/128), 256, 0, stream>>>(
                        xdbl, 96, dt_w + (size_t)pd * CDI * CR, CR, dt_b + pd * CDI, Abuf, CDI, CR);
                    scan_k<<<CDI / 16, 256, 0, stream>>>(
                        Abuf, uc, xdbl, Zbuf, A_log + pd * CDI * CNS, Dsk + pd * CDI, uc, d);
                    gemm_nt<128,128,16,8,8,0,false,false><<<dim3(CDM/128, rows/128), 256, 0, stream>>>(
                        uc, CDI, out_w + (size_t)pd * CDM * CDI, CDI, nullptr, Zbuf, CDM, CDI);
                    if (d == 0)
                        gemm_nt<128,128,16,8,8,0,true,true><<<dim3(CDM/128, rows/128), 256, 0, stream>>>(
                            Zbuf, CDM, pw, 2048, proj_b + l * CDM, hsb, CDM, CDM);
                    else
                        gemm_nt<128,128,16,8,8,0,false,true><<<dim3(CDM/128, rows/128), 256, 0, stream>>>(
                            Zbuf, CDM, pw, 2048, nullptr, hsb, CDM, CDM);
                }
            }
        }
        layernorm_k<<<CB * CL, 256, 0, stream>>>(hs, fn_w, fn_b, (float*)d_out);
    }
}

// Round 4
// 13231.699 us; speedup vs baseline: 1.1564x; 1.1564x over previous
//
#include <hip/hip_runtime.h>
#include <cstddef>

// Problem constants (match reference)
constexpr int CB  = 4;      // batch
constexpr int CL  = 2048;   // seq len
constexpr int CDM = 1024;   // model dim
constexpr int CDI = 2048;   // inner dim
constexpr int CNS = 16;     // state dim
constexpr int CR  = 64;     // dt rank

// ---------------------------------------------------------------------------
// Generic fp32 GEMM (NT): C[m,n] = act(sum_k A[m,k]*W[n,k] + bias[n]) (+= opt)
// A: (M, lda) row-major, W: (N, ldw) row-major (both k-contiguous).
// Grid: (N/BN, M/BM), block 256 = 16x16 threads, micro-tile TM x TN interleaved.
// ACT: 0 = none, 1 = softplus. Shapes chosen so no bounds checks needed.
// ---------------------------------------------------------------------------
template<int BM, int BN, int BK, int TM, int TN, int ACT, bool BIAS, bool ACC>
__global__ __launch_bounds__(256)
void gemm_nt(const float* __restrict__ A, int lda,
             const float* __restrict__ W, int ldw,
             const float* __restrict__ bias,
             float* __restrict__ C, int ldc, int Ksz)
{
    __shared__ float As[BM][BK + 4];
    __shared__ float Ws[BN][BK + 4];
    const int tid = threadIdx.x;
    const int tx  = tid & 15;          // n-dim thread coord
    const int ty  = tid >> 4;          // m-dim thread coord
    const int m0  = blockIdx.y * BM;
    const int n0  = blockIdx.x * BN;

    float acc[TM][TN] = {};

    const int rA = tid >> 2;           // 4 threads per row, float4 along k
    const int kq = (tid & 3) * 4;

    for (int k0 = 0; k0 < Ksz; k0 += BK) {
        for (int r = rA; r < BM; r += 64) {
            float4 v = *(const float4*)(A + (size_t)(m0 + r) * lda + (k0 + kq));
            *(float4*)&As[r][kq] = v;
        }
        for (int r = rA; r < BN; r += 64) {
            float4 v = *(const float4*)(W + (size_t)(n0 + r) * ldw + (k0 + kq));
            *(float4*)&Ws[r][kq] = v;
        }
        __syncthreads();
#pragma unroll
        for (int k4 = 0; k4 < BK / 4; ++k4) {
            float4 a4[TM], w4[TN];
#pragma unroll
            for (int i = 0; i < TM; ++i) a4[i] = *(const float4*)&As[ty + 16 * i][k4 * 4];
#pragma unroll
            for (int j = 0; j < TN; ++j) w4[j] = *(const float4*)&Ws[tx + 16 * j][k4 * 4];
#pragma unroll
            for (int i = 0; i < TM; ++i)
#pragma unroll
                for (int j = 0; j < TN; ++j) {
                    acc[i][j] += a4[i].x * w4[j].x;
                    acc[i][j] += a4[i].y * w4[j].y;
                    acc[i][j] += a4[i].z * w4[j].z;
                    acc[i][j] += a4[i].w * w4[j].w;
                }
        }
        __syncthreads();
    }

#pragma unroll
    for (int i = 0; i < TM; ++i) {
        const int m = m0 + ty + 16 * i;
#pragma unroll
        for (int j = 0; j < TN; ++j) {
            const int n = n0 + tx + 16 * j;
            float v = acc[i][j];
            if (BIAS) v += bias[n];
            if (ACT == 1) v = (v > 20.f) ? v : log1pf(__expf(v));  // softplus
            const size_t off = (size_t)m * ldc + n;
            if (ACC) C[off] += v; else C[off] = v;
        }
    }
}

// ---------------------------------------------------------------------------
// LayerNorm over last dim (1024). One block (256 thr) per row, float4 per thr.
// ---------------------------------------------------------------------------
__global__ __launch_bounds__(256)
void layernorm_k(const float* __restrict__ in, const float* __restrict__ w,
                 const float* __restrict__ b, float* __restrict__ out)
{
    __shared__ float red[4];
    const int row = blockIdx.x, tid = threadIdx.x;
    const float4 x = *(const float4*)(in + (size_t)row * CDM + tid * 4);

    float s = x.x + x.y + x.z + x.w;
#pragma unroll
    for (int off = 32; off >= 1; off >>= 1) s += __shfl_xor(s, off, 64);
    if ((tid & 63) == 0) red[tid >> 6] = s;
    __syncthreads();
    const float mu = (red[0] + red[1] + red[2] + red[3]) * (1.f / CDM);
    __syncthreads();

    float4 d;
    d.x = x.x - mu; d.y = x.y - mu; d.z = x.z - mu; d.w = x.w - mu;
    float ss = d.x * d.x + d.y * d.y + d.z * d.z + d.w * d.w;
#pragma unroll
    for (int off = 32; off >= 1; off >>= 1) ss += __shfl_xor(ss, off, 64);
    if ((tid & 63) == 0) red[tid >> 6] = ss;
    __syncthreads();
    const float var = (red[0] + red[1] + red[2] + red[3]) * (1.f / CDM);
    const float rs = rsqrtf(var + 1e-5f);

    const float4 wv = *(const float4*)(w + tid * 4);
    const float4 bv = *(const float4*)(b + tid * 4);
    float4 o;
    o.x = d.x * rs * wv.x + bv.x;
    o.y = d.y * rs * wv.y + bv.y;
    o.z = d.z * rs * wv.z + bv.z;
    o.w = d.w * rs * wv.w + bv.w;
    *(float4*)(out + (size_t)row * CDM + tid * 4) = o;
}

// ---------------------------------------------------------------------------
// Causal depthwise conv (K=4) + SiLU. rev=1 uses the anti-causal window.
// ---------------------------------------------------------------------------
__global__ __launch_bounds__(256)
void conv_silu_k(const float* __restrict__ u, const float* __restrict__ cw,
                 const float* __restrict__ cb, float* __restrict__ uc, int rev)
{
    const int idx = blockIdx.x * 256 + threadIdx.x;
    const int c = idx & (CDI - 1);
    const int t = (idx >> 11) & (CL - 1);
    const int b = idx >> 22;
    const size_t rb = (size_t)b * CL;

    float s = cb[c];
#pragma unroll
    for (int k = 0; k < 4; ++k) {
        const int tsrc = rev ? (t + 3 - k) : (t - 3 + k);
        if (tsrc >= 0 && tsrc < CL)
            s += cw[c * 4 + k] * u[(rb + tsrc) * CDI + c];
    }
    s = s / (1.f + __expf(-s));   // silu
    uc[(rb + t) * CDI + c] = s;
}

// ---------------------------------------------------------------------------
// Chunked-parallel selective scan. One block per (b,c): 256 thr = 16 states
// (n = tid&15) x 16 time-chunks (g = tid>>4) of TC=128 steps.
//   phase 1: each thread scans its chunk from h=0, tracking (prod a, h_local)
//   stitch : 16-step serial LDS scan gives each chunk its incoming h
//   phase 2: re-scan with true h; shfl-sum over n; fused D-skip + z-gate.
// Serial depth 2048 -> 2x128; grid 512 -> 8192 blocks (was latency-bound at
// 22% occupancy, 16% VALUBusy, 2% HBM). y overwrites uc in place (each block
// owns channel c exclusively; reads of uv precede lane-0's write per step).
// ---------------------------------------------------------------------------
__global__ __launch_bounds__(256)
void scan_chunked_k(const float* __restrict__ dt, const float* __restrict__ ucin,
                    const float* __restrict__ xdbl, const float* __restrict__ z,
                    const float* __restrict__ A_log, const float* __restrict__ Dsk,
                    float* __restrict__ yout, int rev)
{
    constexpr int NCH = 16, TC = CL / NCH;   // 16 chunks x 128 steps
    __shared__ float ap_s[NCH][16], he_s[NCH][16], hin_s[NCH][16];
    const int tid = threadIdx.x;
    const int n = tid & 15, g = tid >> 4;
    const int c = blockIdx.x & (CDI - 1);
    const int b = blockIdx.x >> 11;          // 0 when grid covers one batch elem
    const size_t rb = (size_t)b * CL;

    const float Acn = -__expf(A_log[c * CNS + n]);
    const int s0 = g * TC;
    const int t0 = rev ? (CL - 1 - s0) : s0;
    const int tstep = rev ? -1 : 1;
    const ptrdiff_t sdt = (ptrdiff_t)tstep * CDI;
    const ptrdiff_t sxb = (ptrdiff_t)tstep * 96;

    // phase 1: local chunk scan from h=0, accumulate a-product
    const float* pdt = dt   + (rb + t0) * CDI + c;
    const float* puc = ucin + (rb + t0) * CDI + c;
    const float* pxb = xdbl + (rb + t0) * 96 + 64 + n;
    float h = 0.f, ap = 1.f;
    for (int i = 0; i < TC; ++i) {
        const float dtv = *pdt, uv = *puc, Bn = *pxb;
        const float da = __expf(dtv * Acn);
        h = da * h + (dtv * uv) * Bn;
        ap *= da;
        pdt += sdt; puc += sdt; pxb += sxb;
    }
    ap_s[g][n] = ap; he_s[g][n] = h;
    __syncthreads();

    // stitch: serial over 16 chunks, parallel over 16 states
    if (tid < 16) {
        float hh = 0.f;
        for (int gg = 0; gg < NCH; ++gg) {
            hin_s[gg][tid] = hh;
            hh = ap_s[gg][tid] * hh + he_s[gg][tid];
        }
    }
    __syncthreads();

    // phase 2: re-scan with true incoming h, emit y
    h = hin_s[g][n];
    const float Dc = Dsk[c];
    pdt = dt   + (rb + t0) * CDI + c;
    puc = ucin + (rb + t0) * CDI + c;
    pxb = xdbl + (rb + t0) * 96 + 64 + n;
    const float* pxc = xdbl + (rb + t0) * 96 + 80 + n;
    const float* pz  = z    + (rb + t0) * CDI + c;
    float*       py  = yout + (rb + t0) * CDI + c;
    for (int i = 0; i < TC; ++i) {
        const float dtv = *pdt, uv = *puc, Bn = *pxb, Cn = *pxc;
        const float da = __expf(dtv * Acn);
        h = da * h + (dtv * uv) * Bn;
        float p = h * Cn;
        p += __shfl_xor(p, 8, 16);
        p += __shfl_xor(p, 4, 16);
        p += __shfl_xor(p, 2, 16);
        p += __shfl_xor(p, 1, 16);
        if (n == 0) {
            const float zv = *pz;
            float yv = p + Dc * uv;
            yv *= zv / (1.f + __expf(-zv));   // * silu(z)
            *py = yv;
        }
        pdt += sdt; puc += sdt; pxb += sxb; pxc += sxb;
        pz += sdt; py += sdt;
    }
}

// ---------------------------------------------------------------------------
extern "C" void kernel_launch(void* const* d_in, const int* in_sizes, int n_in,
                              void* d_out, int out_size, void* d_ws, size_t ws_size,
                              hipStream_t stream)
{
    (void)in_sizes; (void)n_in; (void)out_size;
    const float* x      = (const float*)d_in[0];
    const float* norm_w = (const float*)d_in[1];
    const float* norm_b = (const float*)d_in[2];
    const float* in_w   = (const float*)d_in[3];
    const float* conv_w = (const float*)d_in[4];
    const float* conv_b = (const float*)d_in[5];
    const float* xp_w   = (const float*)d_in[6];
    const float* dt_w   = (const float*)d_in[7];
    const float* dt_b   = (const float*)d_in[8];
    const float* A_log  = (const float*)d_in[9];
    const float* Dsk    = (const float*)d_in[10];
    const float* out_w  = (const float*)d_in[11];
    const float* proj_w = (const float*)d_in[12];
    const float* proj_b = (const float*)d_in[13];
    const float* fn_w   = (const float*)d_in[14];
    const float* fn_b   = (const float*)d_in[15];

    float* ws   = (float*)d_ws;
    float* hbuf = (float*)d_out;                 // LN output scratch (32 MB, free)

    // Fast path footprint (floats): hs 8M | A(u/dtb) 16M | Z(z/tmp) 16M |
    // uc 16M | xdbl 0.75M  => 59,506,688 floats = 227 MB (proven to fit, R3)
    const size_t F_HS = 8u * 1024 * 1024;
    const size_t F_BIG = 16u * 1024 * 1024;
    const size_t need_fast = (F_HS + 3 * F_BIG + 786432) * sizeof(float);

    if (ws_size >= need_fast) {
        // ----------------- fast path: full batch per kernel ----------------
        float* hs   = ws;                        // (B,L,DM) residual
        float* Abuf = hs   + F_HS;               // u, then dtb   (B,L,DI)
        float* Zbuf = Abuf + F_BIG;              // z, then tmp   (B,L,DI)
        float* uc   = Zbuf + F_BIG;              // conv out / y  (B,L,DI)
        float* xdbl = uc   + F_BIG;              // (B,L,96) delta|B|C

        hipMemcpyAsync(hs, x, F_HS * sizeof(float), hipMemcpyDeviceToDevice, stream);
        const int rows = CB * CL;  // 8192

        for (int l = 0; l < 2; ++l) {
            layernorm_k<<<rows, 256, 0, stream>>>(hs, norm_w + l * CDM, norm_b + l * CDM, hbuf);
            for (int d = 0; d < 2; ++d) {
                const int pd = l * 2 + d;
                const float* iw = in_w + (size_t)pd * 4096 * CDM;
                // u = h @ in_w[:2048]^T ; z = h @ in_w[2048:4096]^T
                gemm_nt<128,128,16,8,8,0,false,false><<<dim3(CDI/128, rows/128), 256, 0, stream>>>(
                    hbuf, CDM, iw, CDM, nullptr, Abuf, CDI, CDM);
                gemm_nt<128,128,16,8,8,0,false,false><<<dim3(CDI/128, rows/128), 256, 0, stream>>>(
                    hbuf, CDM, iw + (size_t)CDI * CDM, CDM, nullptr, Zbuf, CDI, CDM);
                conv_silu_k<<<(rows * CDI) / 256, 256, 0, stream>>>(
                    Abuf, conv_w + pd * CDI * 4, conv_b + pd * CDI, uc, d);
                gemm_nt<64,96,16,4,6,0,false,false><<<dim3(1, rows/64), 256, 0, stream>>>(
                    uc, CDI, xp_w + (size_t)pd * 96 * CDI, CDI, nullptr, xdbl, 96, CDI);
                gemm_nt<128,128,16,8,8,1,true,false><<<dim3(CDI/128, rows/128), 256, 0, stream>>>(
                    xdbl, 96, dt_w + (size_t)pd * CDI * CR, CR, dt_b + pd * CDI, Abuf, CDI, CR);
                scan_chunked_k<<<CB * CDI, 256, 0, stream>>>(
                    Abuf, uc, xdbl, Zbuf, A_log + pd * CDI * CNS, Dsk + pd * CDI, uc, d);
                // tmp = y @ out_w^T   (reuses Zbuf; z is dead after the scan)
                gemm_nt<128,128,16,8,8,0,false,false><<<dim3(CDM/128, rows/128), 256, 0, stream>>>(
                    uc, CDI, out_w + (size_t)pd * CDM * CDI, CDI, nullptr, Zbuf, CDM, CDI);
                // hs += tmp @ proj_w[:, d*1024:+1024]^T  (+ proj_b once, on d==0)
                const float* pw = proj_w + (size_t)l * CDM * 2048 + d * CDM;
                if (d == 0)
                    gemm_nt<128,128,16,8,8,0,true,true><<<dim3(CDM/128, rows/128), 256, 0, stream>>>(
                        Zbuf, CDM, pw, 2048, proj_b + l * CDM, hs, CDM, CDM);
                else
                    gemm_nt<128,128,16,8,8,0,false,true><<<dim3(CDM/128, rows/128), 256, 0, stream>>>(
                        Zbuf, CDM, pw, 2048, nullptr, hs, CDM, CDM);
            }
        }
        layernorm_k<<<rows, 256, 0, stream>>>(hs, fn_w, fn_b, (float*)d_out);
    } else {
        // -------------- chunked path: one batch element at a time ----------
        // Footprint: hs 8M | A 4M | Z 4M | uc 4M | xdbl 0.1875M = 81 MB
        const size_t F_B = 4u * 1024 * 1024;
        float* hs   = ws;
        float* Abuf = hs   + F_HS;
        float* Zbuf = Abuf + F_B;
        float* uc   = Zbuf + F_B;
        float* xdbl = uc   + F_B;

        hipMemcpyAsync(hs, x, F_HS * sizeof(float), hipMemcpyDeviceToDevice, stream);
        const int rows = CL;  // 2048 per batch element

        for (int l = 0; l < 2; ++l) {
            layernorm_k<<<CB * CL, 256, 0, stream>>>(hs, norm_w + l * CDM, norm_b + l * CDM, hbuf);
            for (int d = 0; d < 2; ++d) {
                const int pd = l * 2 + d;
                const float* iw = in_w + (size_t)pd * 4096 * CDM;
                const float* pw = proj_w + (size_t)l * CDM * 2048 + d * CDM;
                for (int b = 0; b < CB; ++b) {
                    const float* hb = hbuf + (size_t)b * CL * CDM;
                    float* hsb = hs + (size_t)b * CL * CDM;
                    gemm_nt<128,128,16,8,8,0,false,false><<<dim3(CDI/128, rows/128), 256, 0, stream>>>(
                        hb, CDM, iw, CDM, nullptr, Abuf, CDI, CDM);
                    gemm_nt<128,128,16,8,8,0,false,false><<<dim3(CDI/128, rows/128), 256, 0, stream>>>(
                        hb, CDM, iw + (size_t)CDI * CDM, CDM, nullptr, Zbuf, CDI, CDM);
                    conv_silu_k<<<(rows * CDI) / 256, 256, 0, stream>>>(
                        Abuf, conv_w + pd * CDI * 4, conv_b + pd * CDI, uc, d);
                    gemm_nt<64,96,16,4,6,0,false,false><<<dim3(1, rows/64), 256, 0, stream>>>(
                        uc, CDI, xp_w + (size_t)pd * 96 * CDI, CDI, nullptr, xdbl, 96, CDI);
                    gemm_nt<128,128,16,8,8,1,true,false><<<dim3(CDI/128, rows/128), 256, 0, stream>>>(
                        xdbl, 96, dt_w + (size_t)pd * CDI * CR, CR, dt_b + pd * CDI, Abuf, CDI, CR);
                    scan_chunked_k<<<CDI, 256, 0, stream>>>(
                        Abuf, uc, xdbl, Zbuf, A_log + pd * CDI * CNS, Dsk + pd * CDI, uc, d);
                    gemm_nt<128,128,16,8,8,0,false,false><<<dim3(CDM/128, rows/128), 256, 0, stream>>>(
                        uc, CDI, out_w + (size_t)pd * CDM * CDI, CDI, nullptr, Zbuf, CDM, CDI);
                    if (d == 0)
                        gemm_nt<128,128,16,8,8,0,true,true><<<dim3(CDM/128, rows/128), 256, 0, stream>>>(
                            Zbuf, CDM, pw, 2048, proj_b + l * CDM, hsb, CDM, CDM);
                    else
                        gemm_nt<128,128,16,8,8,0,false,true><<<dim3(CDM/128, rows/128), 256, 0, stream>>>(
                            Zbuf, CDM, pw, 2048, nullptr, hsb, CDM, CDM);
                }
            }
        }
        layernorm_k<<<CB * CL, 256, 0, stream>>>(hs, fn_w, fn_b, (float*)d_out);
    }
}

// Round 5
// 9473.183 us; speedup vs baseline: 1.6151x; 1.3968x over previous
//
#include <hip/hip_runtime.h>
#include <cstddef>

// Problem constants (match reference)
constexpr int CB  = 4;      // batch
constexpr int CL  = 2048;   // seq len
constexpr int CDM = 1024;   // model dim
constexpr int CDI = 2048;   // inner dim
constexpr int CNS = 16;     // state dim
constexpr int CR  = 64;     // dt rank

// ---------------------------------------------------------------------------
// Generic fp32 GEMM (NT): C[m,n] = act(sum_k A[m,k]*W[n,k] + bias[n]) (+= opt)
// ---------------------------------------------------------------------------
template<int BM, int BN, int BK, int TM, int TN, int ACT, bool BIAS, bool ACC>
__global__ __launch_bounds__(256)
void gemm_nt(const float* __restrict__ A, int lda,
             const float* __restrict__ W, int ldw,
             const float* __restrict__ bias,
             float* __restrict__ C, int ldc, int Ksz)
{
    __shared__ float As[BM][BK + 4];
    __shared__ float Ws[BN][BK + 4];
    const int tid = threadIdx.x;
    const int tx  = tid & 15;          // n-dim thread coord
    const int ty  = tid >> 4;          // m-dim thread coord
    const int m0  = blockIdx.y * BM;
    const int n0  = blockIdx.x * BN;

    float acc[TM][TN] = {};

    const int rA = tid >> 2;           // 4 threads per row, float4 along k
    const int kq = (tid & 3) * 4;

    for (int k0 = 0; k0 < Ksz; k0 += BK) {
        for (int r = rA; r < BM; r += 64) {
            float4 v = *(const float4*)(A + (size_t)(m0 + r) * lda + (k0 + kq));
            *(float4*)&As[r][kq] = v;
        }
        for (int r = rA; r < BN; r += 64) {
            float4 v = *(const float4*)(W + (size_t)(n0 + r) * ldw + (k0 + kq));
            *(float4*)&Ws[r][kq] = v;
        }
        __syncthreads();
#pragma unroll
        for (int k4 = 0; k4 < BK / 4; ++k4) {
            float4 a4[TM], w4[TN];
#pragma unroll
            for (int i = 0; i < TM; ++i) a4[i] = *(const float4*)&As[ty + 16 * i][k4 * 4];
#pragma unroll
            for (int j = 0; j < TN; ++j) w4[j] = *(const float4*)&Ws[tx + 16 * j][k4 * 4];
#pragma unroll
            for (int i = 0; i < TM; ++i)
#pragma unroll
                for (int j = 0; j < TN; ++j) {
                    acc[i][j] += a4[i].x * w4[j].x;
                    acc[i][j] += a4[i].y * w4[j].y;
                    acc[i][j] += a4[i].z * w4[j].z;
                    acc[i][j] += a4[i].w * w4[j].w;
                }
        }
        __syncthreads();
    }

#pragma unroll
    for (int i = 0; i < TM; ++i) {
        const int m = m0 + ty + 16 * i;
#pragma unroll
        for (int j = 0; j < TN; ++j) {
            const int n = n0 + tx + 16 * j;
            float v = acc[i][j];
            if (BIAS) v += bias[n];
            if (ACT == 1) v = (v > 20.f) ? v : log1pf(__expf(v));  // softplus
            const size_t off = (size_t)m * ldc + n;
            if (ACC) C[off] += v; else C[off] = v;
        }
    }
}

// ---------------------------------------------------------------------------
// LayerNorm over last dim (1024). One block (256 thr) per row, float4 per thr.
// ---------------------------------------------------------------------------
__global__ __launch_bounds__(256)
void layernorm_k(const float* __restrict__ in, const float* __restrict__ w,
                 const float* __restrict__ b, float* __restrict__ out)
{
    __shared__ float red[4];
    const int row = blockIdx.x, tid = threadIdx.x;
    const float4 x = *(const float4*)(in + (size_t)row * CDM + tid * 4);

    float s = x.x + x.y + x.z + x.w;
#pragma unroll
    for (int off = 32; off >= 1; off >>= 1) s += __shfl_xor(s, off, 64);
    if ((tid & 63) == 0) red[tid >> 6] = s;
    __syncthreads();
    const float mu = (red[0] + red[1] + red[2] + red[3]) * (1.f / CDM);
    __syncthreads();

    float4 d;
    d.x = x.x - mu; d.y = x.y - mu; d.z = x.z - mu; d.w = x.w - mu;
    float ss = d.x * d.x + d.y * d.y + d.z * d.z + d.w * d.w;
#pragma unroll
    for (int off = 32; off >= 1; off >>= 1) ss += __shfl_xor(ss, off, 64);
    if ((tid & 63) == 0) red[tid >> 6] = ss;
    __syncthreads();
    const float var = (red[0] + red[1] + red[2] + red[3]) * (1.f / CDM);
    const float rs = rsqrtf(var + 1e-5f);

    const float4 wv = *(const float4*)(w + tid * 4);
    const float4 bv = *(const float4*)(b + tid * 4);
    float4 o;
    o.x = d.x * rs * wv.x + bv.x;
    o.y = d.y * rs * wv.y + bv.y;
    o.z = d.z * rs * wv.z + bv.z;
    o.w = d.w * rs * wv.w + bv.w;
    *(float4*)(out + (size_t)row * CDM + tid * 4) = o;
}

// ---------------------------------------------------------------------------
// Causal depthwise conv (K=4) + SiLU. rev=1 uses the anti-causal window.
// ---------------------------------------------------------------------------
__global__ __launch_bounds__(256)
void conv_silu_k(const float* __restrict__ u, const float* __restrict__ cw,
                 const float* __restrict__ cb, float* __restrict__ uc, int rev)
{
    const int idx = blockIdx.x * 256 + threadIdx.x;
    const int c = idx & (CDI - 1);
    const int t = (idx >> 11) & (CL - 1);
    const int b = idx >> 22;
    const size_t rb = (size_t)b * CL;

    float s = cb[c];
#pragma unroll
    for (int k = 0; k < 4; ++k) {
        const int tsrc = rev ? (t + 3 - k) : (t - 3 + k);
        if (tsrc >= 0 && tsrc < CL)
            s += cw[c * 4 + k] * u[(rb + tsrc) * CDI + c];
    }
    s = s / (1.f + __expf(-s));   // silu
    uc[(rb + t) * CDI + c] = s;
}

// ---------------------------------------------------------------------------
// Coalesced chunked-parallel selective scan.
// R4 post-mortem: previous scan (block per (b,c), channel fixed) overfetched
// ~10x (FETCH 2.65 GB/dispatch vs 0.26 ideal) because dt/uc/z/y used 4 B of
// each 64 B line. Fix: block = (b, 16-channel tile); 256 thr = 16 channels
// (tid&15 -> consecutive, coalesced) x 16 time-chunks. Each thread keeps all
// 16 states in registers; B/C are per-(b,t) float4 broadcasts.
//   phase 1: scan own chunk from h=0, keep h[16], ap[16]
//   stitch : (c,n)-parallel serial loop over 16 chunks in LDS (pad 17)
//   phase 2: re-scan with true h, in-register C-dot, D-skip + z-gate.
// y overwrites uc in place (thread reads uv before writing y at same index).
// ---------------------------------------------------------------------------
__global__ __launch_bounds__(256)
void scan_tiled_k(const float* __restrict__ dt, const float* __restrict__ ucin,
                  const float* __restrict__ xdbl, const float* __restrict__ z,
                  const float* __restrict__ A_log, const float* __restrict__ Dsk,
                  float* __restrict__ yout, int rev)
{
    constexpr int NCH = 16, TC = CL / NCH;   // 16 chunks x 128 steps
    __shared__ float ap_s[NCH][16][17];      // padded: conflict-free
    __shared__ float he_s[NCH][16][17];
    const int tid = threadIdx.x;
    const int cl  = tid & 15;                // channel within tile (fast axis)
    const int g   = tid >> 4;                // time chunk
    const int c   = ((blockIdx.x & 127) << 4) + cl;
    const int b   = blockIdx.x >> 7;         // 0 when grid covers one batch elem
    const size_t rb = (size_t)b * CL;

    float Acn[CNS];
    *(float4*)&Acn[0]  = *(const float4*)(A_log + c * CNS);
    *(float4*)&Acn[4]  = *(const float4*)(A_log + c * CNS + 4);
    *(float4*)&Acn[8]  = *(const float4*)(A_log + c * CNS + 8);
    *(float4*)&Acn[12] = *(const float4*)(A_log + c * CNS + 12);
#pragma unroll
    for (int n = 0; n < CNS; ++n) Acn[n] = -__expf(Acn[n]);

    const int s0 = g * TC;
    const int t0 = rev ? (CL - 1 - s0) : s0;
    const ptrdiff_t st  = rev ? -1 : 1;
    const ptrdiff_t sdt = st * CDI;
    const ptrdiff_t sxb = st * 96;

    // phase 1: local chunk scan from h=0
    const float* pdt = dt   + (rb + t0) * CDI + c;
    const float* puc = ucin + (rb + t0) * CDI + c;
    const float* pxb = xdbl + (rb + t0) * 96 + 64;   // B row base

    float h[CNS] = {}, ap[CNS];
#pragma unroll
    for (int n = 0; n < CNS; ++n) ap[n] = 1.f;

    for (int i = 0; i < TC; ++i) {
        const float dtv = *pdt, uv = *puc;
        const float du = dtv * uv;
        float Bv[CNS];
        *(float4*)&Bv[0]  = *(const float4*)(pxb);
        *(float4*)&Bv[4]  = *(const float4*)(pxb + 4);
        *(float4*)&Bv[8]  = *(const float4*)(pxb + 8);
        *(float4*)&Bv[12] = *(const float4*)(pxb + 12);
#pragma unroll
        for (int n = 0; n < CNS; ++n) {
            const float da = __expf(dtv * Acn[n]);
            h[n] = da * h[n] + du * Bv[n];
            ap[n] *= da;
        }
        pdt += sdt; puc += sdt; pxb += sxb;
    }
#pragma unroll
    for (int n = 0; n < CNS; ++n) { ap_s[g][cl][n] = ap[n]; he_s[g][cl][n] = h[n]; }
    __syncthreads();

    // stitch: thread owns (c2, n2); serial over 16 chunks; hin in-place in ap_s
    {
        const int n2 = tid & 15, c2 = tid >> 4;
        float hh = 0.f;
        for (int gg = 0; gg < NCH; ++gg) {
            const float a = ap_s[gg][c2][n2], e = he_s[gg][c2][n2];
            ap_s[gg][c2][n2] = hh;
            hh = a * hh + e;
        }
    }
    __syncthreads();

    // phase 2: re-scan with true incoming h, emit y
#pragma unroll
    for (int n = 0; n < CNS; ++n) h[n] = ap_s[g][cl][n];
    const float Dc = Dsk[c];
    pdt = dt   + (rb + t0) * CDI + c;
    puc = ucin + (rb + t0) * CDI + c;
    pxb = xdbl + (rb + t0) * 96 + 64;
    const float* pz = z    + (rb + t0) * CDI + c;
    float*       py = yout + (rb + t0) * CDI + c;

    for (int i = 0; i < TC; ++i) {
        const float dtv = *pdt, uv = *puc;
        const float du = dtv * uv;
        float Bv[CNS], Cv[CNS];
        *(float4*)&Bv[0]  = *(const float4*)(pxb);
        *(float4*)&Bv[4]  = *(const float4*)(pxb + 4);
        *(float4*)&Bv[8]  = *(const float4*)(pxb + 8);
        *(float4*)&Bv[12] = *(const float4*)(pxb + 12);
        *(float4*)&Cv[0]  = *(const float4*)(pxb + 16);
        *(float4*)&Cv[4]  = *(const float4*)(pxb + 20);
        *(float4*)&Cv[8]  = *(const float4*)(pxb + 24);
        *(float4*)&Cv[12] = *(const float4*)(pxb + 28);
        float acc = 0.f;
#pragma unroll
        for (int n = 0; n < CNS; ++n) {
            const float da = __expf(dtv * Acn[n]);
            h[n] = da * h[n] + du * Bv[n];
            acc += h[n] * Cv[n];
        }
        const float zv = *pz;
        float yv = acc + Dc * uv;
        yv *= zv / (1.f + __expf(-zv));   // * silu(z)
        *py = yv;
        pdt += sdt; puc += sdt; pxb += sxb; pz += sdt; py += sdt;
    }
}

// ---------------------------------------------------------------------------
extern "C" void kernel_launch(void* const* d_in, const int* in_sizes, int n_in,
                              void* d_out, int out_size, void* d_ws, size_t ws_size,
                              hipStream_t stream)
{
    (void)in_sizes; (void)n_in; (void)out_size;
    const float* x      = (const float*)d_in[0];
    const float* norm_w = (const float*)d_in[1];
    const float* norm_b = (const float*)d_in[2];
    const float* in_w   = (const float*)d_in[3];
    const float* conv_w = (const float*)d_in[4];
    const float* conv_b = (const float*)d_in[5];
    const float* xp_w   = (const float*)d_in[6];
    const float* dt_w   = (const float*)d_in[7];
    const float* dt_b   = (const float*)d_in[8];
    const float* A_log  = (const float*)d_in[9];
    const float* Dsk    = (const float*)d_in[10];
    const float* out_w  = (const float*)d_in[11];
    const float* proj_w = (const float*)d_in[12];
    const float* proj_b = (const float*)d_in[13];
    const float* fn_w   = (const float*)d_in[14];
    const float* fn_b   = (const float*)d_in[15];

    float* ws   = (float*)d_ws;
    float* hbuf = (float*)d_out;                 // LN output scratch (32 MB, free)

    // Fast path footprint (floats): hs 8M | A(u/dtb) 16M | Z(z/tmp) 16M |
    // uc 16M | xdbl 0.75M  => 59,506,688 floats = 227 MB (proven to fit, R3)
    const size_t F_HS = 8u * 1024 * 1024;
    const size_t F_BIG = 16u * 1024 * 1024;
    const size_t need_fast = (F_HS + 3 * F_BIG + 786432) * sizeof(float);

    if (ws_size >= need_fast) {
        // ----------------- fast path: full batch per kernel ----------------
        float* hs   = ws;                        // (B,L,DM) residual
        float* Abuf = hs   + F_HS;               // u, then dtb   (B,L,DI)
        float* Zbuf = Abuf + F_BIG;              // z, then tmp   (B,L,DI)
        float* uc   = Zbuf + F_BIG;              // conv out / y  (B,L,DI)
        float* xdbl = uc   + F_BIG;              // (B,L,96) delta|B|C

        hipMemcpyAsync(hs, x, F_HS * sizeof(float), hipMemcpyDeviceToDevice, stream);
        const int rows = CB * CL;  // 8192

        for (int l = 0; l < 2; ++l) {
            layernorm_k<<<rows, 256, 0, stream>>>(hs, norm_w + l * CDM, norm_b + l * CDM, hbuf);
            for (int d = 0; d < 2; ++d) {
                const int pd = l * 2 + d;
                const float* iw = in_w + (size_t)pd * 4096 * CDM;
                // u = h @ in_w[:2048]^T ; z = h @ in_w[2048:4096]^T
                gemm_nt<128,128,16,8,8,0,false,false><<<dim3(CDI/128, rows/128), 256, 0, stream>>>(
                    hbuf, CDM, iw, CDM, nullptr, Abuf, CDI, CDM);
                gemm_nt<128,128,16,8,8,0,false,false><<<dim3(CDI/128, rows/128), 256, 0, stream>>>(
                    hbuf, CDM, iw + (size_t)CDI * CDM, CDM, nullptr, Zbuf, CDI, CDM);
                conv_silu_k<<<(rows * CDI) / 256, 256, 0, stream>>>(
                    Abuf, conv_w + pd * CDI * 4, conv_b + pd * CDI, uc, d);
                gemm_nt<64,96,16,4,6,0,false,false><<<dim3(1, rows/64), 256, 0, stream>>>(
                    uc, CDI, xp_w + (size_t)pd * 96 * CDI, CDI, nullptr, xdbl, 96, CDI);
                gemm_nt<128,128,16,8,8,1,true,false><<<dim3(CDI/128, rows/128), 256, 0, stream>>>(
                    xdbl, 96, dt_w + (size_t)pd * CDI * CR, CR, dt_b + pd * CDI, Abuf, CDI, CR);
                scan_tiled_k<<<CB * (CDI / 16), 256, 0, stream>>>(
                    Abuf, uc, xdbl, Zbuf, A_log + pd * CDI * CNS, Dsk + pd * CDI, uc, d);
                // tmp = y @ out_w^T   (reuses Zbuf; z is dead after the scan)
                gemm_nt<128,128,16,8,8,0,false,false><<<dim3(CDM/128, rows/128), 256, 0, stream>>>(
                    uc, CDI, out_w + (size_t)pd * CDM * CDI, CDI, nullptr, Zbuf, CDM, CDI);
                // hs += tmp @ proj_w[:, d*1024:+1024]^T  (+ proj_b once, on d==0)
                const float* pw = proj_w + (size_t)l * CDM * 2048 + d * CDM;
                if (d == 0)
                    gemm_nt<128,128,16,8,8,0,true,true><<<dim3(CDM/128, rows/128), 256, 0, stream>>>(
                        Zbuf, CDM, pw, 2048, proj_b + l * CDM, hs, CDM, CDM);
                else
                    gemm_nt<128,128,16,8,8,0,false,true><<<dim3(CDM/128, rows/128), 256, 0, stream>>>(
                        Zbuf, CDM, pw, 2048, nullptr, hs, CDM, CDM);
            }
        }
        layernorm_k<<<rows, 256, 0, stream>>>(hs, fn_w, fn_b, (float*)d_out);
    } else {
        // -------------- chunked path: one batch element at a time ----------
        // Footprint: hs 8M | A 4M | Z 4M | uc 4M | xdbl 0.1875M = 81 MB
        const size_t F_B = 4u * 1024 * 1024;
        float* hs   = ws;
        float* Abuf = hs   + F_HS;
        float* Zbuf = Abuf + F_B;
        float* uc   = Zbuf + F_B;
        float* xdbl = uc   + F_B;

        hipMemcpyAsync(hs, x, F_HS * sizeof(float), hipMemcpyDeviceToDevice, stream);
        const int rows = CL;  // 2048 per batch element

        for (int l = 0; l < 2; ++l) {
            layernorm_k<<<CB * CL, 256, 0, stream>>>(hs, norm_w + l * CDM, norm_b + l * CDM, hbuf);
            for (int d = 0; d < 2; ++d) {
                const int pd = l * 2 + d;
                const float* iw = in_w + (size_t)pd * 4096 * CDM;
                const float* pw = proj_w + (size_t)l * CDM * 2048 + d * CDM;
                for (int b = 0; b < CB; ++b) {
                    const float* hb = hbuf + (size_t)b * CL * CDM;
                    float* hsb = hs + (size_t)b * CL * CDM;
                    gemm_nt<128,128,16,8,8,0,false,false><<<dim3(CDI/128, rows/128), 256, 0, stream>>>(
                        hb, CDM, iw, CDM, nullptr, Abuf, CDI, CDM);
                    gemm_nt<128,128,16,8,8,0,false,false><<<dim3(CDI/128, rows/128), 256, 0, stream>>>(
                        hb, CDM, iw + (size_t)CDI * CDM, CDM, nullptr, Zbuf, CDI, CDM);
                    conv_silu_k<<<(rows * CDI) / 256, 256, 0, stream>>>(
                        Abuf, conv_w + pd * CDI * 4, conv_b + pd * CDI, uc, d);
                    gemm_nt<64,96,16,4,6,0,false,false><<<dim3(1, rows/64), 256, 0, stream>>>(
                        uc, CDI, xp_w + (size_t)pd * 96 * CDI, CDI, nullptr, xdbl, 96, CDI);
                    gemm_nt<128,128,16,8,8,1,true,false><<<dim3(CDI/128, rows/128), 256, 0, stream>>>(
                        xdbl, 96, dt_w + (size_t)pd * CDI * CR, CR, dt_b + pd * CDI, Abuf, CDI, CR);
                    scan_tiled_k<<<CDI / 16, 256, 0, stream>>>(
                        Abuf, uc, xdbl, Zbuf, A_log + pd * CDI * CNS, Dsk + pd * CDI, uc, d);
                    gemm_nt<128,128,16,8,8,0,false,false><<<dim3(CDM/128, rows/128), 256, 0, stream>>>(
                        uc, CDI, out_w + (size_t)pd * CDM * CDI, CDI, nullptr, Zbuf, CDM, CDI);
                    if (d == 0)
                        gemm_nt<128,128,16,8,8,0,true,true><<<dim3(CDM/128, rows/128), 256, 0, stream>>>(
                            Zbuf, CDM, pw, 2048, proj_b + l * CDM, hsb, CDM, CDM);
                    else
                        gemm_nt<128,128,16,8,8,0,false,true><<<dim3(CDM/128, rows/128), 256, 0, stream>>>(
                            Zbuf, CDM, pw, 2048, nullptr, hsb, CDM, CDM);
                }
            }
        }
        layernorm_k<<<CB * CL, 256, 0, stream>>>(hs, fn_w, fn_b, (float*)d_out);
    }
}